// Round 1
// baseline (174.719 us; speedup 1.0000x reference)
//
#include <hip/hip_runtime.h>
#include <math.h>

#define HDIM 64
#define VPB 64              // vars per bucket (bucket = dst >> 6)
#define NBR 1600            // partition LDS array sizing (>= NB = 1563)
#define MAXCAP 1072         // max edges per bucket (mean 800, +9.6 sigma)
#define PKSHIFT 25          // pk = (vl << 25) | src ; requires src < 2^25
#define PKMASK 0x1FFFFFF
#define SSTR 36             // sums LDS var stride (dwords): 16B-aligned, <=2-way banks

typedef __attribute__((ext_vector_type(8))) short s8v;   // 8 bf16 (4 VGPRs)
typedef __attribute__((ext_vector_type(4))) float f4v;   // MFMA C/D

__device__ __forceinline__ int pkbf(float lo, float hi) {   // pack 2 f32 -> 2 bf16
    unsigned ul = __float_as_uint(lo) + 0x8000u;
    unsigned uh = __float_as_uint(hi) + 0x8000u;
    return (int)((ul >> 16) | (uh & 0xffff0000u));
}

// ---------------------------------------------------------------------------
// Pass 1 (r10 version, ~5-10 us): 1024-thread blocks for latency tolerance.
// LDS histogram -> one returning global atomic per nonzero (block,bucket) ->
// LDS rank -> 4B scatter store of packed records.
// ---------------------------------------------------------------------------
__global__ __launch_bounds__(1024) void k_partition(
        const int* __restrict__ src, const int* __restrict__ dst,
        int* __restrict__ pairs, int* __restrict__ bcur,
        int E, int NB, int CAP) {
    __shared__ int hist[NBR], cur[NBR], gb[NBR];
    int t = threadIdx.x;
    int e0 = blockIdx.x << 12;

    for (int j = t; j < NBR; j += 1024) { hist[j] = 0; cur[j] = 0; }
    __syncthreads();

    int pk[4], bb[4];
    #pragma unroll
    for (int k = 0; k < 4; ++k) {
        int e = e0 + (k << 10) + t;
        pk[k] = -1; bb[k] = 0;
        if (e < E) {
            int d = dst[e];
            bb[k] = d >> 6;
            pk[k] = ((d & (VPB - 1)) << PKSHIFT) | src[e];
            atomicAdd(&hist[bb[k]], 1);
        }
    }
    __syncthreads();
    for (int j = t; j < NB; j += 1024) {
        int h = hist[j];
        if (h) gb[j] = j * CAP + atomicAdd(&bcur[j << 4], h);
    }
    __syncthreads();
    #pragma unroll
    for (int k = 0; k < 4; ++k) {
        if (pk[k] != -1) {
            int b = bb[k];
            int r = atomicAdd(&cur[b], 1);
            int g = gb[b] + r;
            if (g < (b + 1) * CAP) pairs[g] = pk[k];
        }
    }
}

// ---------------------------------------------------------------------------
// Pass 2: sort (validated) + gather (validated) + MFMA epilogue.
// Phase A: per var-pair, quarter-wave float4 gather -> combine -> pack bf16
//          sums into wave-private LDS (stride SSTR dwords, 16B aligned).
// Phase B: A-frags = W rows (bf16, k-major per m120-verified A layout);
//          B-frags = sums via 2 ds_read_b128; 8 MFMAs -> all 64x16 outputs.
//          C layout (m89-verified): row=4q+reg(+16i), col=var c.
//          LN = 16-wide per-lane sum + 4 shfls for ALL 16 vars. float4 store.
// R1: __launch_bounds__(256,8) — gather is latency-bound (MfmaUtil 0.5%,
//     VALUBusy 21%, HBM 34%, Occ 50%): double resident waves 16->32/CU.
//     LDS 18944B x 8 blocks = 148 KiB <= 160 KiB; VGPR 36 <= 64 cap.
// ---------------------------------------------------------------------------
__global__ __launch_bounds__(256, 8) void k_fused(
        const float* __restrict__ x, const int* __restrict__ pairs,
        const int* __restrict__ bcur, const float* __restrict__ W,
        const float* __restrict__ b, const float* __restrict__ gamma,
        const float* __restrict__ beta, float* __restrict__ out,
        int V, int CAP) {
    __shared__ int pbuf[MAXCAP];
    __shared__ int sidx[MAXCAP];
    __shared__ int vcnt[VPB], vcur[VPB], voff[VPB];
    __shared__ int sums[4 * 16 * SSTR];      // bf16 sums, wave-private regions
    int t = threadIdx.x;
    int blk = blockIdx.x;
    int base = blk * CAP;
    int cnt = bcur[blk << 4]; if (cnt > CAP) cnt = CAP;

    if (t < VPB) vcnt[t] = 0;
    __syncthreads();
    for (int e = t; e < cnt; e += 256) {
        int pk = pairs[base + e];
        pbuf[e] = pk;
        atomicAdd(&vcnt[((unsigned)pk) >> PKSHIFT], 1);
    }
    __syncthreads();
    if (t < 64) {                            // wave 0: shfl exclusive scan
        int c0 = vcnt[t];
        int pre = c0;
        #pragma unroll
        for (int off = 1; off < 64; off <<= 1) {
            int u = __shfl_up(pre, off, 64);
            if (t >= off) pre += u;
        }
        voff[t] = pre - c0;
        vcur[t] = pre - c0;
    }
    __syncthreads();
    for (int e = t; e < cnt; e += 256) {
        int pk = pbuf[e];
        int slot = atomicAdd(&vcur[((unsigned)pk) >> PKSHIFT], 1);
        sidx[slot] = pk & PKMASK;
    }
    __syncthreads();

    int wv = t >> 6, lane = t & 63, q = lane >> 4, c = lane & 15;
    int sbase = wv * (16 * SSTR);

    // -------- Phase A: gather raw sums for this wave's 16 vars --------------
    for (int j = 0; j < 8; ++j) {
        int lv0 = j << 1, lv1 = lv0 + 1;
        int vl0 = (wv << 4) + lv0, vl1 = vl0 + 1;
        int start0 = voff[vl0], dg0 = vcnt[vl0];
        int start1 = voff[vl1], dg1 = vcnt[vl1];

        float a0x = 0, a0y = 0, a0z = 0, a0w = 0;
        float a1x = 0, a1y = 0, a1z = 0, a1w = 0;
        int n = dg0 > dg1 ? dg0 : dg1;
        for (int t0 = 0; t0 < n; t0 += 16) {
            #pragma unroll
            for (int k = 0; k < 4; ++k) {
                int ii = t0 + (k << 2) + q;
                if (ii < dg0) {
                    int s = sidx[start0 + ii];          // 16-lane-uniform broadcast
                    const float4 xv = *(const float4*)(x + ((size_t)s << 6) + (c << 2));
                    a0x += xv.x; a0y += xv.y; a0z += xv.z; a0w += xv.w;
                }
                if (ii < dg1) {
                    int s = sidx[start1 + ii];
                    const float4 xv = *(const float4*)(x + ((size_t)s << 6) + (c << 2));
                    a1x += xv.x; a1y += xv.y; a1z += xv.z; a1w += xv.w;
                }
            }
        }
        a0x += __shfl_xor(a0x, 16, 64); a1x += __shfl_xor(a1x, 16, 64);
        a0y += __shfl_xor(a0y, 16, 64); a1y += __shfl_xor(a1y, 16, 64);
        a0z += __shfl_xor(a0z, 16, 64); a1z += __shfl_xor(a1z, 16, 64);
        a0w += __shfl_xor(a0w, 16, 64); a1w += __shfl_xor(a1w, 16, 64);
        a0x += __shfl_xor(a0x, 32, 64); a1x += __shfl_xor(a1x, 32, 64);
        a0y += __shfl_xor(a0y, 32, 64); a1y += __shfl_xor(a1y, 32, 64);
        a0z += __shfl_xor(a0z, 32, 64); a1z += __shfl_xor(a1z, 32, 64);
        a0w += __shfl_xor(a0w, 32, 64); a1w += __shfl_xor(a1w, 32, 64);

        if (q == 0) {                        // lane c writes cols 4c..4c+3 (bf16)
            int o0 = sbase + lv0 * SSTR + (c << 1);
            sums[o0]     = pkbf(a0x, a0y);
            sums[o0 + 1] = pkbf(a0z, a0w);
            int o1 = sbase + lv1 * SSTR + (c << 1);
            sums[o1]     = pkbf(a1x, a1y);
            sums[o1 + 1] = pkbf(a1z, a1w);
        }
    }
    __builtin_amdgcn_wave_barrier();         // wave-private LDS; DS ops in-order

    // -------- Phase B: 8 MFMAs -> 64 outputs x 16 vars ----------------------
    union { int i4[4]; s8v v; } af[4][2];    // A: W[16i+c][h*32+8q .. +7]
    #pragma unroll
    for (int i = 0; i < 4; ++i)
        #pragma unroll
        for (int hh = 0; hh < 2; ++hh) {
            const float* wp = W + (((i << 4) + c) << 6) + (hh << 5) + (q << 3);
            float4 wa = *(const float4*)wp;
            float4 wb = *(const float4*)(wp + 4);
            af[i][hh].i4[0] = pkbf(wa.x, wa.y);
            af[i][hh].i4[1] = pkbf(wa.z, wa.w);
            af[i][hh].i4[2] = pkbf(wb.x, wb.y);
            af[i][hh].i4[3] = pkbf(wb.z, wb.w);
        }
    int so = sbase + c * SSTR + (q << 2);    // B: sums[var c][8q..8q+7] (+16dw: k hi)
    union { int4 i; s8v v; } bf1, bf2;
    bf1.i = *(const int4*)&sums[so];
    bf2.i = *(const int4*)&sums[so + 16];

    f4v acc[4];
    #pragma unroll
    for (int i = 0; i < 4; ++i) {
        acc[i] = (f4v){0.f, 0.f, 0.f, 0.f};
        acc[i] = __builtin_amdgcn_mfma_f32_16x16x32_bf16(af[i][0].v, bf1.v, acc[i], 0, 0, 0);
        acc[i] = __builtin_amdgcn_mfma_f32_16x16x32_bf16(af[i][1].v, bf2.v, acc[i], 0, 0, 0);
    }

    float dv  = (float)vcnt[(wv << 4) + c];  // degree of var c (this wave)
    float inv = 1.0f / (dv + 1e-6f);
    float tb  = dv * inv;
    float hreg[16];
    float s1 = 0.f, s2 = 0.f;
    #pragma unroll
    for (int i = 0; i < 4; ++i) {            // h = relu((W@sum + deg*b)*inv)
        float4 bv = *(const float4*)(b + (i << 4) + (q << 2));
        float hv;
        hv = fmaxf(fmaf(bv.x, tb, acc[i][0] * inv), 0.f); hreg[(i<<2)+0] = hv; s1 += hv; s2 = fmaf(hv, hv, s2);
        hv = fmaxf(fmaf(bv.y, tb, acc[i][1] * inv), 0.f); hreg[(i<<2)+1] = hv; s1 += hv; s2 = fmaf(hv, hv, s2);
        hv = fmaxf(fmaf(bv.z, tb, acc[i][2] * inv), 0.f); hreg[(i<<2)+2] = hv; s1 += hv; s2 = fmaf(hv, hv, s2);
        hv = fmaxf(fmaf(bv.w, tb, acc[i][3] * inv), 0.f); hreg[(i<<2)+3] = hv; s1 += hv; s2 = fmaf(hv, hv, s2);
    }
    s1 += __shfl_xor(s1, 16, 64); s1 += __shfl_xor(s1, 32, 64);
    s2 += __shfl_xor(s2, 16, 64); s2 += __shfl_xor(s2, 32, 64);
    float mu   = s1 * (1.0f / 64.0f);
    float var  = fmaxf(s2 * (1.0f / 64.0f) - mu * mu, 0.0f);
    float rstd = rsqrtf(var + 1e-5f);
    float c0n  = -mu * rstd;

    int v = blk * VPB + (wv << 4) + c;
    if (v < V) {
        #pragma unroll
        for (int i = 0; i < 4; ++i) {
            float4 gv  = *(const float4*)(gamma + (i << 4) + (q << 2));
            float4 btv = *(const float4*)(beta  + (i << 4) + (q << 2));
            float4 o;
            o.x = fmaf(fmaf(hreg[(i<<2)+0], rstd, c0n), gv.x, btv.x);
            o.y = fmaf(fmaf(hreg[(i<<2)+1], rstd, c0n), gv.y, btv.y);
            o.z = fmaf(fmaf(hreg[(i<<2)+2], rstd, c0n), gv.z, btv.z);
            o.w = fmaf(fmaf(hreg[(i<<2)+3], rstd, c0n), gv.w, btv.w);
            *(float4*)(out + ((size_t)v << 6) + (i << 4) + (q << 2)) = o;
        }
    }
}

extern "C" void kernel_launch(void* const* d_in, const int* in_sizes, int n_in,
                              void* d_out, int out_size, void* d_ws, size_t ws_size,
                              hipStream_t stream) {
    const float* x_con = (const float*)d_in[0];
    const int*   src   = (const int*)d_in[1];
    const int*   dst   = (const int*)d_in[2];
    const float* W     = (const float*)d_in[4];
    const float* b     = (const float*)d_in[5];
    const float* gamma = (const float*)d_in[6];
    const float* beta  = (const float*)d_in[7];
    float* out = (float*)d_out;

    int E = in_sizes[1];
    int V = out_size / HDIM;

    int NB = (V + VPB - 1) / VPB;            // 1563 buckets of 64 vars
    int avg = (E + NB - 1) / NB;             // ~800 edges/bucket
    int CAP = avg + (avg >> 3) + 160;        // +~9.6 sigma headroom
    CAP = (CAP + 15) & ~15;
    if (CAP > MAXCAP) CAP = MAXCAP;

    // ws layout: [pairs: NB*CAP int][bcur: NB*16 int padded]
    int* pairs = (int*)d_ws;
    int* bcur  = pairs + (size_t)NB * CAP;

    hipMemsetAsync(bcur, 0, (size_t)NB * 16 * sizeof(int), stream);
    k_partition<<<(E + 4095) / 4096, 1024, 0, stream>>>(src, dst, pairs, bcur, E, NB, CAP);
    k_fused<<<NB, 256, 0, stream>>>(x_con, pairs, bcur, W, b, gamma, beta, out, V, CAP);
}